// Round 6
// baseline (113.034 us; speedup 1.0000x reference)
//
#include <hip/hip_runtime.h>

typedef unsigned int uint;
typedef unsigned short ushort;
typedef __attribute__((ext_vector_type(8))) short bf16x8;   // MFMA A/B frag (8 bf16)
typedef __attribute__((ext_vector_type(4))) float f32x4;    // MFMA C/D frag
typedef __attribute__((ext_vector_type(8))) unsigned short ushort8v;

// Problem constants
#define C_IN   48
#define C3     144
#define HW     56
#define SSP    3136
#define DW     49
#define DPAD   64            // padded head dim; yf cols 49..63 zero, yfT row 56 ones
#define NROWS  9216

// Attention R17 = R12 compute body + 4-deep K/V ring with a barrier every
// TWO iterations. Rationale: per-iter __syncthreads lockstepped all 8
// waves into the same pipe phase (QK-MFMA / exp2-VALU / PV-MFMA convoys);
// pair-barriers let waves drift one iter apart so VALU and MFMA phases of
// different waves overlap. LDS 65536 B -> still 2 blocks/CU (16 waves/CU).
#define NSPLIT 12            // key splits
#define TPS    12            // tiles per split = 144/NSPLIT

#define CSC 0.02944245f      // 1/(49*ln2): exp2(qk*CSC)=exp(qk/49)

// ws layout (bytes):
//   yf    bf16 [9216][64]    : 0        .. 1179648
//   yfT   bf16 [64][9216]    : 1179648  .. 2359296   (keys kappa-permuted per 64-tile)
//   opart bf16 [12][49][9216]: 2359296  .. 13197312
//   esum  f32  [12][9216]    : 13197312 .. 13639680
#define YF_B    0
#define YFT_B   1179648
#define OPART_B 2359296
#define ESUM_B  (OPART_B + NSPLIT * DW * NROWS * 2)

// Key permutation (within each 64-key tile):
//   LDS V position p holds physical key kappa(p) = {p5, p2, p4, p3, p1, p0}
//   (bit vector msb..lsb). Then the PV B-frag element jj for lane (q,c),
//   k-position 32*nc + 8*q + jj, is exactly the QK output register
//   s[2*nc + (jj>>2)][mt][jj&3] — lane-local, no shuffle, no LDS.
//   Kernel 1 stores yfT column at pi = kappa^{-1}:
//   pi(k) = (k&32) | ((k&12)<<1) | ((k&16)>>2) | (k&3); pi preserves bits 0-1.

__device__ __forceinline__ ushort f32_to_bf16_rne(float x) {
  uint b = __float_as_uint(x);
  b += 0x7fffu + ((b >> 16) & 1u);
  return (ushort)(b >> 16);
}
__device__ __forceinline__ float bf16_to_f32(ushort u) {
  return __uint_as_float(((uint)u) << 16);
}
__device__ __forceinline__ void async_copy16(const void* g, void* l) {
  __builtin_amdgcn_global_load_lds(
      (const __attribute__((address_space(1))) unsigned int*)g,
      (__attribute__((address_space(3))) unsigned int*)l, 16, 0, 0);
}

// Depthwise conv inner body. interior (wave-uniform) => branch-free fully
// unrolled path; identical FMA order to the checked path on interior
// threads -> bitwise-identical output.
template <int KS>
__device__ __forceinline__ float dwconv_val(const float* __restrict__ xc,
                                            const float* __restrict__ wk,
                                            int h, int w, bool interior) {
  constexpr int P = KS / 2;
  float val = 0.f;
  if (interior) {
#pragma unroll
    for (int dy = 0; dy < KS; dy++) {
      const float* xr = xc + (h + dy - P) * HW;
      const float* wr = wk + dy * KS;
#pragma unroll
      for (int dx = 0; dx < KS; dx++)
        val += xr[w + dx - P] * wr[dx];
    }
  } else {
#pragma unroll
    for (int dy = 0; dy < KS; dy++) {
      int hy = h + dy - P;
      if (hy < 0 || hy >= HW) continue;
      const float* xr = xc + hy * HW;
      const float* wr = wk + dy * KS;
#pragma unroll
      for (int dx = 0; dx < KS; dx++) {
        int wx = w + dx - P;
        if (wx < 0 || wx >= HW) continue;
        val += xr[wx] * wr[dx];
      }
    }
  }
  return val;
}

// ---------------------------------------------------------------------------
// Kernel 1: depthwise convs, thread per (r,t); 2304 blocks.
// A wave (64 lanes) = one row r = one (window g, channel) -> kernel size
// and interior-ness are wave-uniform. Interior windows take a branch-free
// fully-unrolled path.
// yf[r][64] written coalesced (linear keys). yfT written via in-block LDS
// transpose at pi-permuted columns (keys kappa-ordered per 64-tile).
// yf cols 49..63 = 0 (K/Q pad); yfT row 56 = 1.0 (softmax denom via PV MFMA).
// ---------------------------------------------------------------------------
__global__ __launch_bounds__(256) void conv_kernel(
    const float* __restrict__ x, const float* __restrict__ w3,
    const float* __restrict__ w5, const float* __restrict__ w7,
    ushort* __restrict__ yf, ushort* __restrict__ yfT) {
  __shared__ ushort tile[4][64];
  const int tid = threadIdx.x;
  const int idx = blockIdx.x * 256 + tid;     // r*64 + t
  const int r = idx >> 6, t = idx & 63;
  const int rr = r & 3;
  const int r0 = r & ~3;

  ushort ov = 0;
  if (t < DW) {
    int g = r / C3, c3 = r - g * C3;
    int flat = g * DW + t;
    int h = flat / HW, w = flat - h * HW;
    int grp = c3 / C_IN, c = c3 - grp * C_IN;
    int nh = g >> 3, nw = g & 7;
    bool interior = ((uint)(nh - 1) <= 5u) && ((uint)(nw - 1) <= 5u);
    const float* xc = x + c * SSP;
    float val;
    if (grp == 0)      val = dwconv_val<3>(xc, w3 + c * 9,  h, w, interior);
    else if (grp == 1) val = dwconv_val<5>(xc, w5 + c * 25, h, w, interior);
    else               val = dwconv_val<7>(xc, w7 + c * 49, h, w, interior);
    ov = f32_to_bf16_rne(val);
  }
  yf[idx] = ov;          // coalesced (pad cols get 0)
  tile[rr][t] = ov;
  __syncthreads();

  if (tid < 64) {
    ushort4 v;
    if (tid == 56) {
      v.x = 0x3F80; v.y = 0x3F80; v.z = 0x3F80; v.w = 0x3F80;  // ones row
    } else {
      v.x = tile[0][tid]; v.y = tile[1][tid];
      v.z = tile[2][tid]; v.w = tile[3][tid];
    }
    // pi-permuted column (pi keeps bits 0-1, r0 % 4 == 0 -> still contiguous)
    const int k6 = r0 & 63;
    const int pcol = (r0 & ~63) | (k6 & 35) | ((k6 & 12) << 1) | ((k6 & 16) >> 2);
    *(ushort4*)&yfT[tid * NROWS + pcol] = v;   // 8B store, 4 consecutive keys
  }
}

// ---------------------------------------------------------------------------
// Kernel 2: MFMA flash attention, P in registers, paired barriers (R17).
// Grid (36, 12): blockIdx.x = 256-query block, blockIdx.y = key split (12
// tiles of 64 keys). All 8 waves share a 4-deep K/V ring; each wave owns
// 32 queries end-to-end.
// LDS: K buf b at b*8192 (b=0..3), V buf b at 32768 + b*8192 = 65536 B.
// K slab s (of 8): d-chunk s, addr s*1024 + key*16 (keys linear).
// V slab s (of 8): key-position chunk s, addr s*1024 + d*16 (keys kappa-ord).
// Pair loop: at pair j fire DMA for tiles 2j+2, 2j+3 (bufs disjoint from
// the pair's compute bufs), compute iters 2j and 2j+1 back-to-back with NO
// intervening barrier (waves drift -> VALU/MFMA phases overlap), then one
// __syncthreads (drains DMA, protects ring reuse).
// QK output s[nt][mt][r] = P[key 16nt+4q+r][query mt*16+c]; with the
// kappa-ordered V, PV B-frag = register repack of exp2(s) — no LDS P.
// yfT row 56 = ones => softmax denominator at d==56.
// ---------------------------------------------------------------------------
__global__ __launch_bounds__(512, 4) void attn_kernel(
    const ushort* __restrict__ yf, const ushort* __restrict__ yfT,
    ushort* __restrict__ opart, float* __restrict__ esum_g) {
  __shared__ __align__(16) char smem[65536];

  const int tid = threadIdx.x;
  const int w = tid >> 6, lane = tid & 63;
  const int q = lane >> 4, c = lane & 15;
  const int m0 = blockIdx.x * 256 + w * 32;   // this wave's 32 queries
  const int sp = blockIdx.y;
  const int base = sp * TPS;

  // Q B-frags (pre-scaled by CSC): 16B loads straight from yf.
  bf16x8 qf[2][2];
#pragma unroll
  for (int mt = 0; mt < 2; mt++)
#pragma unroll
    for (int ds = 0; ds < 2; ds++) {
      bf16x8 raw = *(const bf16x8*)&yf[(m0 + mt * 16 + c) * 64 + ds * 32 + q * 8];
      short tmp[8];
#pragma unroll
      for (int j = 0; j < 8; j++)
        tmp[j] = (short)f32_to_bf16_rne(bf16_to_f32((ushort)raw[j]) * CSC);
      qf[mt][ds] = *(bf16x8*)tmp;
    }

  f32x4 o[4][2];
#pragma unroll
  for (int dt = 0; dt < 4; dt++)
#pragma unroll
    for (int mt = 0; mt < 2; mt++) o[dt][mt] = (f32x4)0.f;

  // this wave's DMA slabs: K slab w, V slab w (8 waves cover 8+8 slabs)
  // ---- prologue: stage tiles 0,1 into ring bufs 0,1 ----
  {
    const int k0 = base * 64;
    async_copy16(yf + (k0 + lane) * 64 + w * 8, smem + w * 1024);
    async_copy16(yfT + lane * NROWS + k0 + w * 8, smem + 32768 + w * 1024);
    const int k1 = (base + 1) * 64;
    async_copy16(yf + (k1 + lane) * 64 + w * 8, smem + 8192 + w * 1024);
    async_copy16(yfT + lane * NROWS + k1 + w * 8,
                 smem + 32768 + 8192 + w * 1024);
  }
  __syncthreads();

  for (int jp = 0; jp < TPS / 2; jp++) {
    // ---- fire DMA for tiles 2jp+2, 2jp+3 into ring bufs (disjoint) ----
    if (jp + 1 < TPS / 2) {
      const int t2 = 2 * jp + 2, t3 = 2 * jp + 3;
      const int k2 = (base + t2) * 64;
      const int k3 = (base + t3) * 64;
      async_copy16(yf + (k2 + lane) * 64 + w * 8,
                   smem + (t2 & 3) * 8192 + w * 1024);
      async_copy16(yfT + lane * NROWS + k2 + w * 8,
                   smem + 32768 + (t2 & 3) * 8192 + w * 1024);
      async_copy16(yf + (k3 + lane) * 64 + w * 8,
                   smem + (t3 & 3) * 8192 + w * 1024);
      async_copy16(yfT + lane * NROWS + k3 + w * 8,
                   smem + 32768 + (t3 & 3) * 8192 + w * 1024);
    }

#pragma unroll
    for (int half = 0; half < 2; half++) {
      const int it = 2 * jp + half;
      const char* Kb = smem + (it & 3) * 8192;
      const char* Vb = smem + 32768 + (it & 3) * 8192;

      __builtin_amdgcn_s_setprio(1);

      // ---- S^T = K . Q^T, exp2, pack to PV B-frags — all in registers ----
      bf16x8 bp[2][2];
#pragma unroll
      for (int nc = 0; nc < 2; nc++) {
        f32x4 s[2][2];
#pragma unroll
        for (int h = 0; h < 2; h++) {
          const int nt = nc * 2 + h;
          bf16x8 a0 = *(const bf16x8*)(Kb + q * 1024 + (nt * 16 + c) * 16);
          bf16x8 a1 = *(const bf16x8*)(Kb + (4 + q) * 1024 + (nt * 16 + c) * 16);
#pragma unroll
          for (int mt = 0; mt < 2; mt++) {
            f32x4 acc = (f32x4)0.f;
            acc = __builtin_amdgcn_mfma_f32_16x16x32_bf16(a0, qf[mt][0], acc, 0, 0, 0);
            acc = __builtin_amdgcn_mfma_f32_16x16x32_bf16(a1, qf[mt][1], acc, 0, 0, 0);
            s[h][mt] = acc;
          }
        }
        // p = exp2(s); bp[mt][nc][jj] = p[2nc + (jj>>2)][mt][jj&3] (lane-local)
#pragma unroll
        for (int mt = 0; mt < 2; mt++) {
          uint u00 = __float_as_uint(__builtin_amdgcn_exp2f(s[0][mt][0]));
          uint u01 = __float_as_uint(__builtin_amdgcn_exp2f(s[0][mt][1]));
          uint u02 = __float_as_uint(__builtin_amdgcn_exp2f(s[0][mt][2]));
          uint u03 = __float_as_uint(__builtin_amdgcn_exp2f(s[0][mt][3]));
          uint u10 = __float_as_uint(__builtin_amdgcn_exp2f(s[1][mt][0]));
          uint u11 = __float_as_uint(__builtin_amdgcn_exp2f(s[1][mt][1]));
          uint u12 = __float_as_uint(__builtin_amdgcn_exp2f(s[1][mt][2]));
          uint u13 = __float_as_uint(__builtin_amdgcn_exp2f(s[1][mt][3]));
          uint4 t4;
          t4.x = (u00 >> 16) | (u01 & 0xffff0000u);
          t4.y = (u02 >> 16) | (u03 & 0xffff0000u);
          t4.z = (u10 >> 16) | (u11 & 0xffff0000u);
          t4.w = (u12 >> 16) | (u13 & 0xffff0000u);
          bp[mt][nc] = *(bf16x8*)&t4;
        }
      }

      // ---- O^T += V^T . P^T (V frags from LDS, kappa-ordered keys) ----
#pragma unroll
      for (int dt = 0; dt < 4; dt++) {
        bf16x8 v0 = *(const bf16x8*)(Vb + q * 1024 + (dt * 16 + c) * 16);
        bf16x8 v1 = *(const bf16x8*)(Vb + (4 + q) * 1024 + (dt * 16 + c) * 16);
        o[dt][0] = __builtin_amdgcn_mfma_f32_16x16x32_bf16(v0, bp[0][0], o[dt][0], 0, 0, 0);
        o[dt][1] = __builtin_amdgcn_mfma_f32_16x16x32_bf16(v0, bp[1][0], o[dt][1], 0, 0, 0);
        o[dt][0] = __builtin_amdgcn_mfma_f32_16x16x32_bf16(v1, bp[0][1], o[dt][0], 0, 0, 0);
        o[dt][1] = __builtin_amdgcn_mfma_f32_16x16x32_bf16(v1, bp[1][1], o[dt][1], 0, 0, 0);
      }

      __builtin_amdgcn_s_setprio(0);
    }

    // one barrier per pair: all waves done reading this pair's bufs;
    // drains next-pair DMA (tiles 2jp+2, 2jp+3 landed).
    if (jp + 1 < TPS / 2) __syncthreads();
  }

  // ---- epilogue: each wave writes its own 32 queries' partials ----
#pragma unroll
  for (int dt = 0; dt < 4; dt++)
#pragma unroll
    for (int mt = 0; mt < 2; mt++)
#pragma unroll
      for (int r = 0; r < 4; r++) {
        int d = dt * 16 + q * 4 + r;
        int m = m0 + mt * 16 + c;
        float v = o[dt][mt][r];
        if (d < DW) {
          opart[(sp * DW + d) * NROWS + m] = f32_to_bf16_rne(v);
        } else if (d == 56) {
          esum_g[sp * NROWS + m] = v;   // softmax denominator (exact f32)
        }
      }
}

// ---------------------------------------------------------------------------
// Kernel 3: fused merge + pointwise + bias + residual.
// Grid (64 windows, 7 t-chunks of 7). For window g all 144 channels are
// contiguous in opart rows: r = g*144 + i. opart reduction reads
// vectorized as ushort8 (16B, all aligned).
// ---------------------------------------------------------------------------
__global__ __launch_bounds__(256) void fuse_pw_kernel(
    const ushort* __restrict__ opart, const float* __restrict__ esum_g,
    const float* __restrict__ x, const float* __restrict__ pw,
    const float* __restrict__ pb, float* __restrict__ out) {
  __shared__ float vb[7 * 145];
  __shared__ float inv_es[144];
  const int g = blockIdx.x, tch = blockIdx.y;
  const int t0 = tch * 7;
  const int tid = threadIdx.x;

  if (tid < 144) {
    int r = g * C3 + tid;
    float e = 0.f;
#pragma unroll
    for (int sp = 0; sp < NSPLIT; sp++) e += esum_g[sp * NROWS + r];
    inv_es[tid] = 1.f / e;
  }
  __syncthreads();

  // 7 tt x 18 chunks of 8 channels = 126 vector tasks
  for (int j = tid; j < 7 * 18; j += 256) {
    int tt = j / 18, ch = j - tt * 18;
    int i0 = ch * 8;
    int t = t0 + tt;
    float acc[8];
#pragma unroll
    for (int k = 0; k < 8; k++) acc[k] = 0.f;
#pragma unroll
    for (int sp = 0; sp < NSPLIT; sp++) {
      ushort8v v = *(const ushort8v*)&opart[(sp * DW + t) * NROWS + g * C3 + i0];
#pragma unroll
      for (int k = 0; k < 8; k++) acc[k] += bf16_to_f32(v[k]);
    }
#pragma unroll
    for (int k = 0; k < 8; k++)
      vb[tt * 145 + i0 + k] = acc[k] * inv_es[i0 + k];
  }
  __syncthreads();

  for (int j = tid; j < C_IN * 7; j += 256) {
    int o = j / 7, tt = j - o * 7;
    int t = t0 + tt;
    const float* pwo = pw + o * C3;
    const float* vrow = &vb[tt * 145];
    float a0 = 0.f, a1 = 0.f, a2 = 0.f, a3 = 0.f;
#pragma unroll
    for (int i = 0; i < C3; i += 4) {
      float4 wv = *(const float4*)&pwo[i];
      a0 += wv.x * vrow[i];
      a1 += wv.y * vrow[i + 1];
      a2 += wv.z * vrow[i + 2];
      a3 += wv.w * vrow[i + 3];
    }
    float acc = (a0 + a1) + (a2 + a3);
    int nh = g >> 3, nw = g & 7;
    int th = t / 7, tw = t - th * 7;
    int oidx = o * SSP + (nh * 7 + th) * HW + (nw * 7 + tw);
    out[oidx] = x[oidx] + pb[o] + acc;
  }
}

// ---------------------------------------------------------------------------
extern "C" void kernel_launch(void* const* d_in, const int* in_sizes, int n_in,
                              void* d_out, int out_size, void* d_ws, size_t ws_size,
                              hipStream_t stream) {
  const float* x  = (const float*)d_in[0];
  const float* w3 = (const float*)d_in[1];
  const float* w5 = (const float*)d_in[2];
  const float* w7 = (const float*)d_in[3];
  const float* pw = (const float*)d_in[4];
  const float* pb = (const float*)d_in[5];
  float* out = (float*)d_out;
  char* ws = (char*)d_ws;

  ushort* yf    = (ushort*)(ws + YF_B);
  ushort* yfT   = (ushort*)(ws + YFT_B);
  ushort* opart = (ushort*)(ws + OPART_B);
  float*  esum  = (float*)(ws + ESUM_B);

  conv_kernel<<<(NROWS * DPAD) / 256, 256, 0, stream>>>(x, w3, w5, w7, yf, yfT);
  attn_kernel<<<dim3(NROWS / 256, NSPLIT), 512, 0, stream>>>(yf, yfT, opart, esum);
  fuse_pw_kernel<<<dim3(64, 7), 256, 0, stream>>>(opart, esum, x, pw, pb, out);
}

// Round 7
// 111.079 us; speedup vs baseline: 1.0176x; 1.0176x over previous
//
#include <hip/hip_runtime.h>

typedef unsigned int uint;
typedef unsigned short ushort;
typedef __attribute__((ext_vector_type(8))) short bf16x8;   // MFMA A/B frag (8 bf16)
typedef __attribute__((ext_vector_type(4))) float f32x4;    // MFMA C/D frag
typedef __attribute__((ext_vector_type(8))) unsigned short ushort8v;

// Problem constants
#define C_IN   48
#define C3     144
#define HW     56
#define SSP    3136
#define DW     49
#define DPAD   64            // padded head dim; yf cols 49..63 zero, yfT row 56 ones
#define NROWS  9216

// Attention R18 = R16 verbatim (session best, 111.09 us): R12 structure
// (8 waves x 32 q, 512 thr, dbuf, 2 blk/CU = 16 waves/CU) + setprio.
// Falsified alternatives: R13 (8 waves/CU, +3.5), R14 (counted vmcnt, 0),
// R15 (64q @ 12 waves/CU, +1.3), R17 (pair-barriers 4-ring, +1.9).
#define NSPLIT 12            // key splits
#define TPS    12            // tiles per split = 144/NSPLIT

#define CSC 0.02944245f      // 1/(49*ln2): exp2(qk*CSC)=exp(qk/49)

// ws layout (bytes):
//   yf    bf16 [9216][64]    : 0        .. 1179648
//   yfT   bf16 [64][9216]    : 1179648  .. 2359296   (keys kappa-permuted per 64-tile)
//   opart bf16 [12][49][9216]: 2359296  .. 13197312
//   esum  f32  [12][9216]    : 13197312 .. 13639680
#define YF_B    0
#define YFT_B   1179648
#define OPART_B 2359296
#define ESUM_B  (OPART_B + NSPLIT * DW * NROWS * 2)

// Key permutation (within each 64-key tile):
//   LDS V position p holds physical key kappa(p) = {p5, p2, p4, p3, p1, p0}
//   (bit vector msb..lsb). Then the PV B-frag element jj for lane (q,c),
//   k-position 32*nc + 8*q + jj, is exactly the QK output register
//   s[2*nc + (jj>>2)][mt][jj&3] — lane-local, no shuffle, no LDS.
//   Kernel 1 stores yfT column at pi = kappa^{-1}:
//   pi(k) = (k&32) | ((k&12)<<1) | ((k&16)>>2) | (k&3); pi preserves bits 0-1.

__device__ __forceinline__ ushort f32_to_bf16_rne(float x) {
  uint b = __float_as_uint(x);
  b += 0x7fffu + ((b >> 16) & 1u);
  return (ushort)(b >> 16);
}
__device__ __forceinline__ float bf16_to_f32(ushort u) {
  return __uint_as_float(((uint)u) << 16);
}
__device__ __forceinline__ void async_copy16(const void* g, void* l) {
  __builtin_amdgcn_global_load_lds(
      (const __attribute__((address_space(1))) unsigned int*)g,
      (__attribute__((address_space(3))) unsigned int*)l, 16, 0, 0);
}

// Depthwise conv inner body. interior (wave-uniform) => branch-free fully
// unrolled path; identical FMA order to the checked path on interior
// threads -> bitwise-identical output.
template <int KS>
__device__ __forceinline__ float dwconv_val(const float* __restrict__ xc,
                                            const float* __restrict__ wk,
                                            int h, int w, bool interior) {
  constexpr int P = KS / 2;
  float val = 0.f;
  if (interior) {
#pragma unroll
    for (int dy = 0; dy < KS; dy++) {
      const float* xr = xc + (h + dy - P) * HW;
      const float* wr = wk + dy * KS;
#pragma unroll
      for (int dx = 0; dx < KS; dx++)
        val += xr[w + dx - P] * wr[dx];
    }
  } else {
#pragma unroll
    for (int dy = 0; dy < KS; dy++) {
      int hy = h + dy - P;
      if (hy < 0 || hy >= HW) continue;
      const float* xr = xc + hy * HW;
      const float* wr = wk + dy * KS;
#pragma unroll
      for (int dx = 0; dx < KS; dx++) {
        int wx = w + dx - P;
        if (wx < 0 || wx >= HW) continue;
        val += xr[wx] * wr[dx];
      }
    }
  }
  return val;
}

// ---------------------------------------------------------------------------
// Kernel 1: depthwise convs, thread per (r,t); 2304 blocks.
// A wave (64 lanes) = one row r = one (window g, channel) -> kernel size
// and interior-ness are wave-uniform. Interior windows take a branch-free
// fully-unrolled path.
// yf[r][64] written coalesced (linear keys). yfT written via in-block LDS
// transpose at pi-permuted columns (keys kappa-ordered per 64-tile).
// yf cols 49..63 = 0 (K/Q pad); yfT row 56 = 1.0 (softmax denom via PV MFMA).
// ---------------------------------------------------------------------------
__global__ __launch_bounds__(256) void conv_kernel(
    const float* __restrict__ x, const float* __restrict__ w3,
    const float* __restrict__ w5, const float* __restrict__ w7,
    ushort* __restrict__ yf, ushort* __restrict__ yfT) {
  __shared__ ushort tile[4][64];
  const int tid = threadIdx.x;
  const int idx = blockIdx.x * 256 + tid;     // r*64 + t
  const int r = idx >> 6, t = idx & 63;
  const int rr = r & 3;
  const int r0 = r & ~3;

  ushort ov = 0;
  if (t < DW) {
    int g = r / C3, c3 = r - g * C3;
    int flat = g * DW + t;
    int h = flat / HW, w = flat - h * HW;
    int grp = c3 / C_IN, c = c3 - grp * C_IN;
    int nh = g >> 3, nw = g & 7;
    bool interior = ((uint)(nh - 1) <= 5u) && ((uint)(nw - 1) <= 5u);
    const float* xc = x + c * SSP;
    float val;
    if (grp == 0)      val = dwconv_val<3>(xc, w3 + c * 9,  h, w, interior);
    else if (grp == 1) val = dwconv_val<5>(xc, w5 + c * 25, h, w, interior);
    else               val = dwconv_val<7>(xc, w7 + c * 49, h, w, interior);
    ov = f32_to_bf16_rne(val);
  }
  yf[idx] = ov;          // coalesced (pad cols get 0)
  tile[rr][t] = ov;
  __syncthreads();

  if (tid < 64) {
    ushort4 v;
    if (tid == 56) {
      v.x = 0x3F80; v.y = 0x3F80; v.z = 0x3F80; v.w = 0x3F80;  // ones row
    } else {
      v.x = tile[0][tid]; v.y = tile[1][tid];
      v.z = tile[2][tid]; v.w = tile[3][tid];
    }
    // pi-permuted column (pi keeps bits 0-1, r0 % 4 == 0 -> still contiguous)
    const int k6 = r0 & 63;
    const int pcol = (r0 & ~63) | (k6 & 35) | ((k6 & 12) << 1) | ((k6 & 16) >> 2);
    *(ushort4*)&yfT[tid * NROWS + pcol] = v;   // 8B store, 4 consecutive keys
  }
}

// ---------------------------------------------------------------------------
// Kernel 2: MFMA flash attention, P in registers (R12 structure + setprio).
// Grid (36, 12): blockIdx.x = 256-query block, blockIdx.y = key split (12
// tiles of 64 keys). All 8 waves share one K/V double-buffer; each wave
// owns 32 queries end-to-end.
// LDS: [Kbuf0 8K][Kbuf1 8K][Vbuf0 8K][Vbuf1 8K] = 32768 B -> 2 blocks/CU.
// K slab s (of 8): d-chunk s, addr s*1024 + key*16 (keys linear).
// V slab s (of 8): key-position chunk s, addr s*1024 + d*16 (keys kappa-ord).
// QK output s[nt][mt][r] = P[key 16nt+4q+r][query mt*16+c]; with the
// kappa-ordered V, PV B-frag = register repack of exp2(s) — no LDS P.
// yfT row 56 = ones => softmax denominator at d==56.
// ---------------------------------------------------------------------------
__global__ __launch_bounds__(512, 4) void attn_kernel(
    const ushort* __restrict__ yf, const ushort* __restrict__ yfT,
    ushort* __restrict__ opart, float* __restrict__ esum_g) {
  __shared__ __align__(16) char smem[32768];

  const int tid = threadIdx.x;
  const int w = tid >> 6, lane = tid & 63;
  const int q = lane >> 4, c = lane & 15;
  const int m0 = blockIdx.x * 256 + w * 32;   // this wave's 32 queries
  const int sp = blockIdx.y;

  // Q B-frags (pre-scaled by CSC): 16B loads straight from yf.
  bf16x8 qf[2][2];
#pragma unroll
  for (int mt = 0; mt < 2; mt++)
#pragma unroll
    for (int ds = 0; ds < 2; ds++) {
      bf16x8 raw = *(const bf16x8*)&yf[(m0 + mt * 16 + c) * 64 + ds * 32 + q * 8];
      short tmp[8];
#pragma unroll
      for (int j = 0; j < 8; j++)
        tmp[j] = (short)f32_to_bf16_rne(bf16_to_f32((ushort)raw[j]) * CSC);
      qf[mt][ds] = *(bf16x8*)tmp;
    }

  f32x4 o[4][2];
#pragma unroll
  for (int dt = 0; dt < 4; dt++)
#pragma unroll
    for (int mt = 0; mt < 2; mt++) o[dt][mt] = (f32x4)0.f;

  // this wave's DMA slabs: K slab w, V slab w (8 waves cover 8+8 slabs)
  // ---- stage tile 0 into buffer 0 ----
  {
    const int k0 = (sp * TPS) * 64;
    async_copy16(yf + (k0 + lane) * 64 + w * 8, smem + w * 1024);
    async_copy16(yfT + lane * NROWS + k0 + w * 8, smem + 16384 + w * 1024);
  }
  __syncthreads();

  for (int it = 0; it < TPS; it++) {
    const int cur = it & 1;
    // ---- fire DMA for next tile into the other buffer ----
    if (it + 1 < TPS) {
      const int k1 = (sp * TPS + it + 1) * 64;
      async_copy16(yf + (k1 + lane) * 64 + w * 8,
                   smem + (cur ^ 1) * 8192 + w * 1024);
      async_copy16(yfT + lane * NROWS + k1 + w * 8,
                   smem + 16384 + (cur ^ 1) * 8192 + w * 1024);
    }

    const char* Kb = smem + cur * 8192;
    const char* Vb = smem + 16384 + cur * 8192;

    __builtin_amdgcn_s_setprio(1);

    // ---- S^T = K . Q^T, exp2, pack to PV B-frags — all in registers ----
    bf16x8 bp[2][2];
#pragma unroll
    for (int nc = 0; nc < 2; nc++) {
      f32x4 s[2][2];
#pragma unroll
      for (int h = 0; h < 2; h++) {
        const int nt = nc * 2 + h;
        bf16x8 a0 = *(const bf16x8*)(Kb + q * 1024 + (nt * 16 + c) * 16);
        bf16x8 a1 = *(const bf16x8*)(Kb + (4 + q) * 1024 + (nt * 16 + c) * 16);
#pragma unroll
        for (int mt = 0; mt < 2; mt++) {
          f32x4 acc = (f32x4)0.f;
          acc = __builtin_amdgcn_mfma_f32_16x16x32_bf16(a0, qf[mt][0], acc, 0, 0, 0);
          acc = __builtin_amdgcn_mfma_f32_16x16x32_bf16(a1, qf[mt][1], acc, 0, 0, 0);
          s[h][mt] = acc;
        }
      }
      // p = exp2(s); bp[mt][nc][jj] = p[2nc + (jj>>2)][mt][jj&3] (lane-local)
#pragma unroll
      for (int mt = 0; mt < 2; mt++) {
        uint u00 = __float_as_uint(__builtin_amdgcn_exp2f(s[0][mt][0]));
        uint u01 = __float_as_uint(__builtin_amdgcn_exp2f(s[0][mt][1]));
        uint u02 = __float_as_uint(__builtin_amdgcn_exp2f(s[0][mt][2]));
        uint u03 = __float_as_uint(__builtin_amdgcn_exp2f(s[0][mt][3]));
        uint u10 = __float_as_uint(__builtin_amdgcn_exp2f(s[1][mt][0]));
        uint u11 = __float_as_uint(__builtin_amdgcn_exp2f(s[1][mt][1]));
        uint u12 = __float_as_uint(__builtin_amdgcn_exp2f(s[1][mt][2]));
        uint u13 = __float_as_uint(__builtin_amdgcn_exp2f(s[1][mt][3]));
        uint4 t4;
        t4.x = (u00 >> 16) | (u01 & 0xffff0000u);
        t4.y = (u02 >> 16) | (u03 & 0xffff0000u);
        t4.z = (u10 >> 16) | (u11 & 0xffff0000u);
        t4.w = (u12 >> 16) | (u13 & 0xffff0000u);
        bp[mt][nc] = *(bf16x8*)&t4;
      }
    }

    // ---- O^T += V^T . P^T (V frags from LDS, kappa-ordered keys) ----
#pragma unroll
    for (int dt = 0; dt < 4; dt++) {
      bf16x8 v0 = *(const bf16x8*)(Vb + q * 1024 + (dt * 16 + c) * 16);
      bf16x8 v1 = *(const bf16x8*)(Vb + (4 + q) * 1024 + (dt * 16 + c) * 16);
      o[dt][0] = __builtin_amdgcn_mfma_f32_16x16x32_bf16(v0, bp[0][0], o[dt][0], 0, 0, 0);
      o[dt][1] = __builtin_amdgcn_mfma_f32_16x16x32_bf16(v0, bp[1][0], o[dt][1], 0, 0, 0);
      o[dt][0] = __builtin_amdgcn_mfma_f32_16x16x32_bf16(v1, bp[0][1], o[dt][0], 0, 0, 0);
      o[dt][1] = __builtin_amdgcn_mfma_f32_16x16x32_bf16(v1, bp[1][1], o[dt][1], 0, 0, 0);
    }

    __builtin_amdgcn_s_setprio(0);

    // barrier: all waves done reading buf[cur]; drains next-tile DMA.
    if (it + 1 < TPS) __syncthreads();
  }

  // ---- epilogue: each wave writes its own 32 queries' partials ----
#pragma unroll
  for (int dt = 0; dt < 4; dt++)
#pragma unroll
    for (int mt = 0; mt < 2; mt++)
#pragma unroll
      for (int r = 0; r < 4; r++) {
        int d = dt * 16 + q * 4 + r;
        int m = m0 + mt * 16 + c;
        float v = o[dt][mt][r];
        if (d < DW) {
          opart[(sp * DW + d) * NROWS + m] = f32_to_bf16_rne(v);
        } else if (d == 56) {
          esum_g[sp * NROWS + m] = v;   // softmax denominator (exact f32)
        }
      }
}

// ---------------------------------------------------------------------------
// Kernel 3: fused merge + pointwise + bias + residual.
// Grid (64 windows, 7 t-chunks of 7). For window g all 144 channels are
// contiguous in opart rows: r = g*144 + i. opart reduction reads
// vectorized as ushort8 (16B, all aligned).
// ---------------------------------------------------------------------------
__global__ __launch_bounds__(256) void fuse_pw_kernel(
    const ushort* __restrict__ opart, const float* __restrict__ esum_g,
    const float* __restrict__ x, const float* __restrict__ pw,
    const float* __restrict__ pb, float* __restrict__ out) {
  __shared__ float vb[7 * 145];
  __shared__ float inv_es[144];
  const int g = blockIdx.x, tch = blockIdx.y;
  const int t0 = tch * 7;
  const int tid = threadIdx.x;

  if (tid < 144) {
    int r = g * C3 + tid;
    float e = 0.f;
#pragma unroll
    for (int sp = 0; sp < NSPLIT; sp++) e += esum_g[sp * NROWS + r];
    inv_es[tid] = 1.f / e;
  }
  __syncthreads();

  // 7 tt x 18 chunks of 8 channels = 126 vector tasks
  for (int j = tid; j < 7 * 18; j += 256) {
    int tt = j / 18, ch = j - tt * 18;
    int i0 = ch * 8;
    int t = t0 + tt;
    float acc[8];
#pragma unroll
    for (int k = 0; k < 8; k++) acc[k] = 0.f;
#pragma unroll
    for (int sp = 0; sp < NSPLIT; sp++) {
      ushort8v v = *(const ushort8v*)&opart[(sp * DW + t) * NROWS + g * C3 + i0];
#pragma unroll
      for (int k = 0; k < 8; k++) acc[k] += bf16_to_f32(v[k]);
    }
#pragma unroll
    for (int k = 0; k < 8; k++)
      vb[tt * 145 + i0 + k] = acc[k] * inv_es[i0 + k];
  }
  __syncthreads();

  for (int j = tid; j < C_IN * 7; j += 256) {
    int o = j / 7, tt = j - o * 7;
    int t = t0 + tt;
    const float* pwo = pw + o * C3;
    const float* vrow = &vb[tt * 145];
    float a0 = 0.f, a1 = 0.f, a2 = 0.f, a3 = 0.f;
#pragma unroll
    for (int i = 0; i < C3; i += 4) {
      float4 wv = *(const float4*)&pwo[i];
      a0 += wv.x * vrow[i];
      a1 += wv.y * vrow[i + 1];
      a2 += wv.z * vrow[i + 2];
      a3 += wv.w * vrow[i + 3];
    }
    float acc = (a0 + a1) + (a2 + a3);
    int nh = g >> 3, nw = g & 7;
    int th = t / 7, tw = t - th * 7;
    int oidx = o * SSP + (nh * 7 + th) * HW + (nw * 7 + tw);
    out[oidx] = x[oidx] + pb[o] + acc;
  }
}

// ---------------------------------------------------------------------------
extern "C" void kernel_launch(void* const* d_in, const int* in_sizes, int n_in,
                              void* d_out, int out_size, void* d_ws, size_t ws_size,
                              hipStream_t stream) {
  const float* x  = (const float*)d_in[0];
  const float* w3 = (const float*)d_in[1];
  const float* w5 = (const float*)d_in[2];
  const float* w7 = (const float*)d_in[3];
  const float* pw = (const float*)d_in[4];
  const float* pb = (const float*)d_in[5];
  float* out = (float*)d_out;
  char* ws = (char*)d_ws;

  ushort* yf    = (ushort*)(ws + YF_B);
  ushort* yfT   = (ushort*)(ws + YFT_B);
  ushort* opart = (ushort*)(ws + OPART_B);
  float*  esum  = (float*)(ws + ESUM_B);

  conv_kernel<<<(NROWS * DPAD) / 256, 256, 0, stream>>>(x, w3, w5, w7, yf, yfT);
  attn_kernel<<<dim3(NROWS / 256, NSPLIT), 512, 0, stream>>>(yf, yfT, opart, esum);
  fuse_pw_kernel<<<dim3(64, 7), 256, 0, stream>>>(opart, esum, x, pw, pb, out);
}